// Round 1
// baseline (111.766 us; speedup 1.0000x reference)
//
#include <hip/hip_runtime.h>
#include <math.h>

namespace {

constexpr int kB   = 2;
constexpr int kNo  = 256;
constexpr int kNi  = 256;
constexpr int kPts = kB * kNo * kNi;   // 131072 points
constexpr int kPlane = kPts;           // stride between (row,col) planes
constexpr int kHid  = 64;
constexpr int kPath = 384;

// ws layout: W2T[384*64] floats | V[384] floats | flag (unsigned)
constexpr size_t kWsW2T  = 0;
constexpr size_t kWsV    = (size_t)kPath * kHid;           // float index
constexpr size_t kWsFlag = kWsV + kPath;                   // float index
constexpr size_t kWsNeedBytes = (kWsFlag + 1) * sizeof(float);

__global__ void prep_kernel(const float* __restrict__ W1,
                            const float* __restrict__ b1,
                            const float* __restrict__ W2,
                            float* __restrict__ W2T,
                            float* __restrict__ V,
                            unsigned* __restrict__ flag)
{
    int t = blockIdx.x * blockDim.x + threadIdx.x;
    if (t < kPath * kHid) {
        int p = t >> 6, i = t & 63;
        W2T[t] = W2[i * kPath + p];
    }
    if (t < kPath) {
        float acc = 0.f;
        for (int i = 0; i < kHid; ++i)
            acc += fmaxf(W1[i], 0.f) * W2[i * kPath + t];
        V[t] = acc;
    }
    if (t == 0) {
        unsigned f = 1u;
        for (int i = 0; i < kHid; ++i)
            if (b1[i] != 0.f) f = 0u;
        *flag = f;
    }
}

template <bool USE_WS>
__global__ __launch_bounds__(256)
void se3_kernel(const float* __restrict__ dm,
                const float* __restrict__ W1,
                const float* __restrict__ b1,
                const float* __restrict__ W2,    // (64,384) original
                const float* __restrict__ b2,
                const float* __restrict__ Q00,   // (1,1,1)
                const float* __restrict__ Q01,   // (1,3,3)
                const float* __restrict__ Q10,   // (3,1,3)
                const float* __restrict__ Q11,   // (3,3,9)
                const float* __restrict__ W2T,   // (384,64) if USE_WS
                const float* __restrict__ V,     // (384)    if USE_WS
                const unsigned* __restrict__ flag,
                float* __restrict__ out)
{
    int pt = blockIdx.x * blockDim.x + threadIdx.x;
    if (pt >= kPts) return;

    float dx = dm[3 * pt + 0];
    float dy = dm[3 * pt + 1];
    float dz = dm[3 * pt + 2];
    float r  = sqrtf(dx * dx + dy * dy + dz * dz);
    float inv = 1.0f / fmaxf(r, 1e-12f);
    float x = dx * inv, y = dy * inv, z = dz * inv;

    const float Y0 = 0.28209479177387814f;
    const float c1 = 0.4886025119029199f;
    float Y1_0 = c1 * y;
    float Y1_1 = c1 * z;
    float Y1_2 = c1 * x;
    float Y2[5];
    Y2[0] = 1.0925484305920792f * x * y;
    Y2[1] = 1.0925484305920792f * y * z;
    Y2[2] = 0.31539156525252005f * (3.f * z * z - 1.f);
    Y2[3] = 1.0925484305920792f * x * z;
    Y2[4] = 0.5462742152960396f * (x * x - y * y);

    // norm = sqrt(2*l_in+1)*sqrt(4*pi)/sqrt(num); num0=4096, num1=8192
    constexpr float kS4pi = 3.5449077018110318f;
    constexpr float kSq3  = 1.7320508075688772f;
    const float n00 = kS4pi / 64.f;
    const float n01 = kSq3 * kS4pi / 64.f;
    const float n10 = kS4pi / 90.50966799187809f;
    const float n11 = kSq3 * kS4pi / 90.50966799187809f;

    // geometry factors (per point, shared across all (u,v))
    float s00 = n00 * Q00[0] * Y0;
    float g01[3], g10[3], G0[9], G1[9], G2[9];
#pragma unroll
    for (int jc = 0; jc < 3; ++jc)
        g01[jc] = n01 * (Q01[jc * 3 + 0] * Y1_0 + Q01[jc * 3 + 1] * Y1_1 +
                         Q01[jc * 3 + 2] * Y1_2);
#pragma unroll
    for (int ir = 0; ir < 3; ++ir)
        g10[ir] = n10 * (Q10[ir * 3 + 0] * Y1_0 + Q10[ir * 3 + 1] * Y1_1 +
                         Q10[ir * 3 + 2] * Y1_2);
#pragma unroll
    for (int e = 0; e < 9; ++e) {
        const float* q = Q11 + e * 9;
        G0[e] = n11 * q[0] * Y0;
        G1[e] = n11 * (q[1] * Y1_0 + q[2] * Y1_1 + q[3] * Y1_2);
        G2[e] = n11 * (q[4] * Y2[0] + q[5] * Y2[1] + q[6] * Y2[2] +
                       q[7] * Y2[3] + q[8] * Y2[4]);
    }

    float* __restrict__ o = out + pt;

    auto emit = [&](int uv, float w00, float w01, float w10,
                    float w110, float w111, float w112) {
        int u = uv >> 3, v = uv & 7;
        int rowu = u * 32;
        o[(size_t)(rowu + v) * kPlane] = s00 * w00;
#pragma unroll
        for (int jc = 0; jc < 3; ++jc)
            o[(size_t)(rowu + 8 + v * 3 + jc) * kPlane] = g01[jc] * w01;
#pragma unroll
        for (int ir = 0; ir < 3; ++ir) {
            int rowb = (8 + u * 3 + ir) * 32;
            o[(size_t)(rowb + v) * kPlane] = g10[ir] * w10;
#pragma unroll
            for (int jc = 0; jc < 3; ++jc) {
                int e = ir * 3 + jc;
                o[(size_t)(rowb + 8 + v * 3 + jc) * kPlane] =
                    fmaf(G0[e], w110, fmaf(G1[e], w111, G2[e] * w112));
            }
        }
    };

    bool fast = false;
    if constexpr (USE_WS) fast = (*flag != 0u);

    if (USE_WS && fast) {
        // b1 == 0 and r >= 0  =>  weights[p] = r * V[p] + b2[p] exactly
#pragma unroll 1
        for (int uv = 0; uv < 64; ++uv) {
            float w00  = fmaf(r, V[uv],            b2[uv]);
            float w01  = fmaf(r, V[64 + uv],       b2[64 + uv]);
            float w10  = fmaf(r, V[128 + uv],      b2[128 + uv]);
            float w110 = fmaf(r, V[192 + 3 * uv],  b2[192 + 3 * uv]);
            float w111 = fmaf(r, V[193 + 3 * uv],  b2[193 + 3 * uv]);
            float w112 = fmaf(r, V[194 + 3 * uv],  b2[194 + 3 * uv]);
            emit(uv, w00, w01, w10, w110, w111, w112);
        }
    } else {
        // general path: honest per-point hidden layer
        float h[kHid];
#pragma unroll
        for (int i = 0; i < kHid; ++i)
            h[i] = fmaxf(fmaf(r, W1[i], b1[i]), 0.f);

#pragma unroll 1
        for (int uv = 0; uv < 64; ++uv) {
            float a00  = b2[uv];
            float a01  = b2[64 + uv];
            float a10  = b2[128 + uv];
            float a110 = b2[192 + 3 * uv];
            float a111 = b2[193 + 3 * uv];
            float a112 = b2[194 + 3 * uv];
            if constexpr (USE_WS) {
                const float* c00  = W2T + (size_t)uv * 64;
                const float* c01  = W2T + (size_t)(64 + uv) * 64;
                const float* c10  = W2T + (size_t)(128 + uv) * 64;
                const float* c110 = W2T + (size_t)(192 + 3 * uv) * 64;
                const float* c111 = c110 + 64;
                const float* c112 = c110 + 128;
#pragma unroll
                for (int i = 0; i < kHid; ++i) {
                    a00  = fmaf(h[i], c00[i],  a00);
                    a01  = fmaf(h[i], c01[i],  a01);
                    a10  = fmaf(h[i], c10[i],  a10);
                    a110 = fmaf(h[i], c110[i], a110);
                    a111 = fmaf(h[i], c111[i], a111);
                    a112 = fmaf(h[i], c112[i], a112);
                }
            } else {
                const float* c = W2 + uv;
#pragma unroll
                for (int i = 0; i < kHid; ++i) {
                    const float* row = c + (size_t)i * kPath;
                    a00  = fmaf(h[i], row[0],              a00);
                    a01  = fmaf(h[i], row[64],             a01);
                    a10  = fmaf(h[i], row[128],            a10);
                    a110 = fmaf(h[i], row[192 + 2 * uv],   a110);
                    a111 = fmaf(h[i], row[193 + 2 * uv],   a111);
                    a112 = fmaf(h[i], row[194 + 2 * uv],   a112);
                }
            }
            emit(uv, a00, a01, a10, a110, a111, a112);
        }
    }
}

} // namespace

extern "C" void kernel_launch(void* const* d_in, const int* in_sizes, int n_in,
                              void* d_out, int out_size, void* d_ws, size_t ws_size,
                              hipStream_t stream)
{
    const float* dm  = (const float*)d_in[0];
    const float* W1  = (const float*)d_in[1];
    const float* b1  = (const float*)d_in[2];
    const float* W2  = (const float*)d_in[3];
    const float* b2  = (const float*)d_in[4];
    const float* Q00 = (const float*)d_in[5];
    const float* Q01 = (const float*)d_in[6];
    const float* Q10 = (const float*)d_in[7];
    const float* Q11 = (const float*)d_in[8];
    float* out = (float*)d_out;

    const int threads = 256;
    const int blocks  = (kPts + threads - 1) / threads;   // 512

    if (ws_size >= kWsNeedBytes) {
        float* W2T = (float*)d_ws;
        float* V   = W2T + kWsV;
        unsigned* flag = (unsigned*)(W2T + kWsFlag);
        prep_kernel<<<(kPath * kHid + threads - 1) / threads, threads, 0, stream>>>(
            W1, b1, W2, W2T, V, flag);
        se3_kernel<true><<<blocks, threads, 0, stream>>>(
            dm, W1, b1, W2, b2, Q00, Q01, Q10, Q11, W2T, V, flag, out);
    } else {
        se3_kernel<false><<<blocks, threads, 0, stream>>>(
            dm, W1, b1, W2, b2, Q00, Q01, Q10, Q11, nullptr, nullptr, nullptr, out);
    }
}